// Round 10
// baseline (348.584 us; speedup 1.0000x reference)
//
#include <hip/hip_runtime.h>
#include <math.h>

#define B_ 4
#define S_ 512
#define D_ 1024
#define H_ 16
#define MCK 8
#define MS 2048
#define BHSS_ ((size_t)16777216)   // B*H*S*S
#define BHS_  ((size_t)32768)

typedef __attribute__((ext_vector_type(8))) __bf16 bf16x8;
typedef __attribute__((ext_vector_type(4))) __bf16 bf16x4;
typedef __attribute__((ext_vector_type(4))) float f32x4;

__device__ __forceinline__ f32x4 mfma16(bf16x8 a, bf16x8 b, f32x4 c) {
  return __builtin_amdgcn_mfma_f32_16x16x32_bf16(a, b, c, 0, 0, 0);
}
__device__ __forceinline__ bf16x8 sq8(bf16x8 x) {
  bf16x8 r;
#pragma unroll
  for (int i = 0; i < 8; ++i) { float f = (float)x[i]; r[i] = (__bf16)(f * f); }
  return r;
}
// (Wh+Wl)^2 elementwise -> bf16
__device__ __forceinline__ bf16x8 sq8s(bf16x8 h, bf16x8 l) {
  bf16x8 r;
#pragma unroll
  for (int i = 0; i < 8; ++i) { float f = (float)h[i] + (float)l[i]; r[i] = (__bf16)(f * f); }
  return r;
}
__device__ __forceinline__ float wave_max(float v) {
#pragma unroll
  for (int o = 32; o; o >>= 1) v = fmaxf(v, __shfl_xor(v, o));
  return v;
}
__device__ __forceinline__ float wave_sum(float v) {
#pragma unroll
  for (int o = 32; o; o >>= 1) v += __shfl_xor(v, o);
  return v;
}

// ---- LDS swizzle helpers: [rows][32] tiles (4 slots of 16B per row) ----
__device__ __forceinline__ void unswz(int u, int& row, int& slot) {
  int row0 = ((u >> 2) ^ (u >> 4)) & 1;
  row = ((u >> 3) << 1) | row0;
  int s0 = (u ^ (u >> 2) ^ (u >> 4)) & 1;
  int s1 = ((u >> 1) ^ (u >> 3)) & 1;
  slot = (s1 << 1) | s0;
}
__device__ __forceinline__ int swz_el(int row, int slot) {
  return ((row * 4 + slot) ^ (row & 7)) * 8;
}
// ---- [rows][64] tiles (8 slots of 16B per row): L = (row*8+slot)^(row&7) ----
__device__ __forceinline__ int swz8_el(int row, int slot) {
  return ((row * 8 + slot) ^ (row & 7)) * 8;
}
__device__ __forceinline__ void unswz8(int u, int& row, int& slot) {
  row = u >> 3;
  slot = (u & 7) ^ (row & 7);
}
__device__ __forceinline__ void glds16(const void* gsrc, void* ldst) {
  __builtin_amdgcn_global_load_lds(
      (const __attribute__((address_space(1))) void*)gsrc,
      (__attribute__((address_space(3))) void*)ldst, 16, 0, 0);
}

// ---------- fused conversion: inputs (loc,scale)->(hi,lo,scale^2); weights W->(hi,lo) ----
__global__ __launch_bounds__(256) void conv_all(
    const float* __restrict__ l0, const float* __restrict__ s0,
    const float* __restrict__ l1, const float* __restrict__ s1,
    const float* __restrict__ l2, const float* __restrict__ s2,
    __bf16* h0, __bf16* o0, __bf16* v0,
    __bf16* h1, __bf16* o1, __bf16* v1,
    __bf16* h2, __bf16* o2, __bf16* v2,
    const float* __restrict__ w0, const float* __restrict__ w1,
    const float* __restrict__ w2, const float* __restrict__ w3,
    __bf16* wh0, __bf16* wo0, __bf16* wh1, __bf16* wo1,
    __bf16* wh2, __bf16* wo2, __bf16* wh3, __bf16* wo3)
{
  const int bid = blockIdx.x;
  if (bid < 3072) {
    const int tn = bid >> 10;
    const size_t i0 = ((size_t)(bid & 1023) * 256 + threadIdx.x) * 8;
    const float* L = tn == 0 ? l0 : tn == 1 ? l1 : l2;
    const float* S = tn == 0 ? s0 : tn == 1 ? s1 : s2;
    __bf16* Hh = tn == 0 ? h0 : tn == 1 ? h1 : h2;
    __bf16* Lo = tn == 0 ? o0 : tn == 1 ? o1 : o2;
    __bf16* V2 = tn == 0 ? v0 : tn == 1 ? v1 : v2;
    float4 x0 = *(const float4*)(L + i0), x1 = *(const float4*)(L + i0 + 4);
    float4 y0 = *(const float4*)(S + i0), y1 = *(const float4*)(S + i0 + 4);
    float xs[8] = {x0.x, x0.y, x0.z, x0.w, x1.x, x1.y, x1.z, x1.w};
    float ys[8] = {y0.x, y0.y, y0.z, y0.w, y1.x, y1.y, y1.z, y1.w};
    bf16x8 hh, ll, vv;
#pragma unroll
    for (int i = 0; i < 8; ++i) {
      __bf16 h = (__bf16)xs[i];
      hh[i] = h;
      ll[i] = (__bf16)(xs[i] - (float)h);
      vv[i] = (__bf16)(ys[i] * ys[i]);
    }
    *(bf16x8*)(Hh + i0) = hh;
    *(bf16x8*)(Lo + i0) = ll;
    *(bf16x8*)(V2 + i0) = vv;
  } else {
    const int b2 = bid - 3072;
    const int tn = b2 >> 9;
    const size_t i0 = ((size_t)(b2 & 511) * 256 + threadIdx.x) * 8;
    const float* W = tn == 0 ? w0 : tn == 1 ? w1 : tn == 2 ? w2 : w3;
    __bf16* Hh = tn == 0 ? wh0 : tn == 1 ? wh1 : tn == 2 ? wh2 : wh3;
    __bf16* Lo = tn == 0 ? wo0 : tn == 1 ? wo1 : tn == 2 ? wo2 : wo3;
    float4 x0 = *(const float4*)(W + i0), x1 = *(const float4*)(W + i0 + 4);
    float xs[8] = {x0.x, x0.y, x0.z, x0.w, x1.x, x1.y, x1.z, x1.w};
    bf16x8 hh, ll;
#pragma unroll
    for (int i = 0; i < 8; ++i) {
      __bf16 h = (__bf16)xs[i];
      hh[i] = h;
      ll[i] = (__bf16)(xs[i] - (float)h);
    }
    *(bf16x8*)(Hh + i0) = hh;
    *(bf16x8*)(Lo + i0) = ll;
  }
}

// ---------- batched dual-GEMM projection (unchanged from R6) ----------
struct PArg {
  const __bf16 *Ah, *Al, *A2, *Wh, *Wl;
  const float* bias;
  __bf16 *P0, *P1, *P2, *P3;
  int epi;
};
struct PArg3 { PArg a[3]; };

#define LDSBUF 14336

__global__ __launch_bounds__(256, 2) void dgemm_qkv(PArg3 P3v)
{
  __shared__ __bf16 lds[2 * LDSBUF];
  const int lin = blockIdx.x + 8 * blockIdx.y + 256 * blockIdx.z;
  const int xcd = lin & 7;
  const int rest = lin >> 3;
  const int mi   = rest & 3;
  const int nblk = (rest >> 2) & 7;
  const int proj = rest >> 5;
  const PArg p = P3v.a[proj];
  const int m0 = (xcd + 8 * mi) * 64;
  const int n0 = nblk * 128;
  const int t = threadIdx.x, lane = t & 63, wid = t >> 6;
  int rA, sA; unswz(t, rA, sA);
  const size_t gA = (size_t)(m0 + rA) * D_ + sA * 8;
  const size_t gW0 = (size_t)(n0 + rA) * D_ + sA * 8;
  int rW1, sW1; unswz(t + 256, rW1, sW1);
  const size_t gW1 = (size_t)(n0 + rW1) * D_ + sW1 * 8;
  const int wofs = wid * 512;
  f32x4 accM[4][2] = {}; f32x4 accV[4][2] = {};
  const int fr = lane & 15, ks = lane >> 4;

  auto STAGE = [&](int buf, int k0) {
    __bf16* L = lds + buf * LDSBUF;
    glds16(p.Ah + gA + k0,  L + 0     + wofs);
    glds16(p.Al + gA + k0,  L + 2048  + wofs);
    glds16(p.A2 + gA + k0,  L + 4096  + wofs);
    glds16(p.Wh + gW0 + k0, L + 6144  + wofs);
    glds16(p.Wl + gW0 + k0, L + 10240 + wofs);
    glds16(p.Wh + gW1 + k0, L + 6144 + 2048 + wofs);
    glds16(p.Wl + gW1 + k0, L + 10240 + 2048 + wofs);
  };

  STAGE(0, 0);
  for (int tt = 0; tt < 32; ++tt) {
    const int cur = tt & 1;
    if (tt < 31) {
      STAGE(cur ^ 1, (tt + 1) * 32);
      asm volatile("s_waitcnt vmcnt(7)" ::: "memory");
    } else {
      asm volatile("s_waitcnt vmcnt(0)" ::: "memory");
    }
    __builtin_amdgcn_s_barrier();
    __builtin_amdgcn_sched_barrier(0);
    const __bf16* L = lds + cur * LDSBUF;
    bf16x8 fah[4], fal[4], fa2[4];
#pragma unroll
    for (int i = 0; i < 4; ++i) {
      int so = swz_el(i * 16 + fr, ks);
      fah[i] = *(const bf16x8*)(L + 0 + so);
      fal[i] = *(const bf16x8*)(L + 2048 + so);
      fa2[i] = *(const bf16x8*)(L + 4096 + so);
    }
#pragma unroll
    for (int j = 0; j < 2; ++j) {
      int so = swz_el(wid * 32 + j * 16 + fr, ks);
      bf16x8 fwh = *(const bf16x8*)(L + 6144 + so);
      bf16x8 fwl = *(const bf16x8*)(L + 10240 + so);
      bf16x8 fw2 = sq8s(fwh, fwl);
#pragma unroll
      for (int i = 0; i < 4; ++i) {
        accM[i][j] = mfma16(fah[i], fwh, accM[i][j]);
        accM[i][j] = mfma16(fah[i], fwl, accM[i][j]);
        accM[i][j] = mfma16(fal[i], fwh, accM[i][j]);
        accV[i][j] = mfma16(fa2[i], fw2, accV[i][j]);
      }
    }
    __builtin_amdgcn_s_barrier();
  }
  const int fq = lane >> 4;
#pragma unroll
  for (int j = 0; j < 2; ++j) {
    const int col = n0 + wid * 32 + j * 16 + fr;
    const float bcol = p.bias[col];
#pragma unroll
    for (int i = 0; i < 4; ++i) {
      const int row0 = m0 + i * 16 + fq * 4;
      f32x4 m_ = accM[i][j], v_ = accV[i][j];
      if (p.epi == 0) {
#pragma unroll
        for (int r = 0; r < 4; ++r) {
          size_t off = (size_t)(row0 + r) * D_ + col;
          float mu = m_[r] + bcol;
          __bf16 h = (__bf16)mu;
          float s = sqrtf(v_[r]) + 1e-6f;
          p.P0[off] = h;
          p.P1[off] = (__bf16)(mu - (float)h);
          p.P2[off] = (__bf16)(mu * mu);
          p.P3[off] = (__bf16)(s * s);
        }
      } else {
        const int b = row0 >> 9, ss0 = row0 & 511;
        const int hh = col >> 6, dd = col & 63;
        size_t base = ((size_t)(b * H_ + hh) * 64 + dd) * S_ + ss0;
        bf16x4 vh, vl, vq;
#pragma unroll
        for (int r = 0; r < 4; ++r) {
          float mu = m_[r] + bcol;
          __bf16 h = (__bf16)mu;
          vh[r] = h;
          vl[r] = (__bf16)(mu - (float)h);
          float s = sqrtf(v_[r]) + 1e-6f;
          vq[r] = (__bf16)(s * s);
        }
        *(bf16x4*)(p.P0 + base) = vh;
        *(bf16x4*)(p.P1 + base) = vl;
        *(bf16x4*)(p.P2 + base) = vq;
      }
    }
  }
}

// ---------- output projection (unchanged from R6) ----------
__global__ __launch_bounds__(256, 2) void dgemm_o(
    const __bf16* __restrict__ Ah, const __bf16* __restrict__ Al, const __bf16* __restrict__ A2,
    const __bf16* __restrict__ Wh, const __bf16* __restrict__ Wl,
    const float* __restrict__ bias, float* __restrict__ O0, float* __restrict__ O1)
{
  __shared__ __bf16 lds[2 * LDSBUF];
  const int lin = blockIdx.x + 8 * blockIdx.y;
  const int xcd = lin & 7;
  const int rest = lin >> 3;
  const int mi   = rest & 3;
  const int nblk = rest >> 2;
  const int m0 = (xcd + 8 * mi) * 64;
  const int n0 = nblk * 128;
  const int t = threadIdx.x, lane = t & 63, wid = t >> 6;
  int rA, sA; unswz(t, rA, sA);
  const size_t gA = (size_t)(m0 + rA) * D_ + sA * 8;
  const size_t gW0 = (size_t)(n0 + rA) * D_ + sA * 8;
  int rW1, sW1; unswz(t + 256, rW1, sW1);
  const size_t gW1 = (size_t)(n0 + rW1) * D_ + sW1 * 8;
  const int wofs = wid * 512;
  f32x4 accM[4][2] = {}; f32x4 accV[4][2] = {};
  const int fr = lane & 15, ks = lane >> 4;

  auto STAGE = [&](int buf, int k0) {
    __bf16* L = lds + buf * LDSBUF;
    glds16(Ah + gA + k0,  L + 0     + wofs);
    glds16(Al + gA + k0,  L + 2048  + wofs);
    glds16(A2 + gA + k0,  L + 4096  + wofs);
    glds16(Wh + gW0 + k0, L + 6144  + wofs);
    glds16(Wl + gW0 + k0, L + 10240 + wofs);
    glds16(Wh + gW1 + k0, L + 6144 + 2048 + wofs);
    glds16(Wl + gW1 + k0, L + 10240 + 2048 + wofs);
  };

  STAGE(0, 0);
  for (int tt = 0; tt < 32; ++tt) {
    const int cur = tt & 1;
    if (tt < 31) {
      STAGE(cur ^ 1, (tt + 1) * 32);
      asm volatile("s_waitcnt vmcnt(7)" ::: "memory");
    } else {
      asm volatile("s_waitcnt vmcnt(0)" ::: "memory");
    }
    __builtin_amdgcn_s_barrier();
    __builtin_amdgcn_sched_barrier(0);
    const __bf16* L = lds + cur * LDSBUF;
    bf16x8 fah[4], fal[4], fa2[4];
#pragma unroll
    for (int i = 0; i < 4; ++i) {
      int so = swz_el(i * 16 + fr, ks);
      fah[i] = *(const bf16x8*)(L + 0 + so);
      fal[i] = *(const bf16x8*)(L + 2048 + so);
      fa2[i] = *(const bf16x8*)(L + 4096 + so);
    }
#pragma unroll
    for (int j = 0; j < 2; ++j) {
      int so = swz_el(wid * 32 + j * 16 + fr, ks);
      bf16x8 fwh = *(const bf16x8*)(L + 6144 + so);
      bf16x8 fwl = *(const bf16x8*)(L + 10240 + so);
      bf16x8 fw2 = sq8s(fwh, fwl);
#pragma unroll
      for (int i = 0; i < 4; ++i) {
        accM[i][j] = mfma16(fah[i], fwh, accM[i][j]);
        accM[i][j] = mfma16(fah[i], fwl, accM[i][j]);
        accM[i][j] = mfma16(fal[i], fwh, accM[i][j]);
        accV[i][j] = mfma16(fa2[i], fw2, accV[i][j]);
      }
    }
    __builtin_amdgcn_s_barrier();
  }
  const int fq = lane >> 4;
#pragma unroll
  for (int j = 0; j < 2; ++j) {
    const int col = n0 + wid * 32 + j * 16 + fr;
    const float bcol = bias[col];
#pragma unroll
    for (int i = 0; i < 4; ++i) {
      const int row0 = m0 + i * 16 + fq * 4;
      f32x4 m_ = accM[i][j], v_ = accV[i][j];
#pragma unroll
      for (int r = 0; r < 4; ++r) {
        size_t off = (size_t)(row0 + r) * D_ + col;
        O0[off] = m_[r] + bcol;
        O1[off] = sqrtf(v_[r]);
      }
    }
  }
}

// ---------- score (unchanged from R9): glds16 single-shot + swizzled reads ----------
__global__ __launch_bounds__(256, 2) void score_mfma(
    const __bf16* __restrict__ qh, const __bf16* __restrict__ ql,
    const __bf16* __restrict__ q2, const __bf16* __restrict__ qv,
    const __bf16* __restrict__ kh, const __bf16* __restrict__ kl,
    const __bf16* __restrict__ k2, const __bf16* __restrict__ kv,
    float* __restrict__ lmu, __bf16* __restrict__ lvar,
    const float* __restrict__ taup)
{
  __shared__ __bf16 S[32768];
  const int t = threadIdx.x;
  const int lane = t & 63, wid = t >> 6;
  const int wm = wid >> 1, wn = wid & 1;
  const int lin = blockIdx.x + 8 * blockIdx.y + 64 * blockIdx.z;
  const int xcd = lin & 7;
  const int rest = lin >> 3;
  const int tile = rest & 63;
  const int bh = xcd + 8 * (rest >> 6);
  const int kk0 = (tile & 7) * 64, q0 = (tile >> 3) * 64;
  const int b = bh >> 4, h = bh & 15;
  const size_t hb = ((size_t)b * S_) * D_ + (size_t)h * 64;
  {
    int r0, s0, r1, s1;
    unswz8(t, r0, s0);
    unswz8(t + 256, r1, s1);
    const __bf16* qa[4] = {qh, ql, q2, qv};
    const __bf16* ka[4] = {kh, kl, k2, kv};
    const int wofs = wid * 512;
#pragma unroll
    for (int a = 0; a < 4; ++a) {
      glds16(qa[a] + hb + (size_t)(q0 + r0) * D_ + s0 * 8, S + a * 4096 + wofs);
      glds16(qa[a] + hb + (size_t)(q0 + r1) * D_ + s1 * 8, S + a * 4096 + 2048 + wofs);
      glds16(ka[a] + hb + (size_t)(kk0 + r0) * D_ + s0 * 8, S + 16384 + a * 4096 + wofs);
      glds16(ka[a] + hb + (size_t)(kk0 + r1) * D_ + s1 * 8, S + 16384 + a * 4096 + 2048 + wofs);
    }
  }
  asm volatile("s_waitcnt vmcnt(0)" ::: "memory");
  __builtin_amdgcn_s_barrier();
  __builtin_amdgcn_sched_barrier(0);

  f32x4 accM[2][2] = {}; f32x4 accV[2][2] = {};
  const int fr = lane & 15, fq = lane >> 4;
#pragma unroll
  for (int ds = 0; ds < 2; ++ds) {
    const int slot = ds * 4 + fq;
    bf16x8 fqh_[2], fql_[2], fq2_[2], fqv_[2];
#pragma unroll
    for (int i = 0; i < 2; ++i) {
      int off = swz8_el(wm * 32 + i * 16 + fr, slot);
      fqh_[i] = *(const bf16x8*)(S + 0 * 4096 + off);
      fql_[i] = *(const bf16x8*)(S + 1 * 4096 + off);
      fq2_[i] = *(const bf16x8*)(S + 2 * 4096 + off);
      fqv_[i] = *(const bf16x8*)(S + 3 * 4096 + off);
    }
#pragma unroll
    for (int j = 0; j < 2; ++j) {
      int koff = swz8_el(wn * 32 + j * 16 + fr, slot);
      bf16x8 fkh_ = *(const bf16x8*)(S + 16384 + 0 * 4096 + koff);
      bf16x8 fkl_ = *(const bf16x8*)(S + 16384 + 1 * 4096 + koff);
      bf16x8 fk2_ = *(const bf16x8*)(S + 16384 + 2 * 4096 + koff);
      bf16x8 fkv_ = *(const bf16x8*)(S + 16384 + 3 * 4096 + koff);
#pragma unroll
      for (int i = 0; i < 2; ++i) {
        accM[i][j] = mfma16(fqh_[i], fkh_, accM[i][j]);
        accM[i][j] = mfma16(fqh_[i], fkl_, accM[i][j]);
        accM[i][j] = mfma16(fql_[i], fkh_, accM[i][j]);
        accV[i][j] = mfma16(fq2_[i], fkv_, accV[i][j]);
        accV[i][j] = mfma16(fqv_[i], fk2_, accV[i][j]);
        accV[i][j] = mfma16(fqv_[i], fkv_, accV[i][j]);
      }
    }
  }
  const float itau = 1.0f / *taup;
#pragma unroll
  for (int i = 0; i < 2; ++i)
#pragma unroll
    for (int j = 0; j < 2; ++j) {
      const int col = kk0 + wn * 32 + j * 16 + fr;
      const int row0 = q0 + wm * 32 + i * 16 + fq * 4;
      f32x4 m_ = accM[i][j], v_ = accV[i][j];
#pragma unroll
      for (int r = 0; r < 4; ++r) {
        size_t off = ((size_t)bh * S_ + row0 + r) * S_ + col;
        lmu[off] = m_[r] * 0.125f * itau;
        float lv = ((v_[r] + 1e-6f) * (1.0f / 64.0f) + 1e-6f) * itau * itau + 1e-6f;
        lvar[off] = (__bf16)lv;
      }
    }
}

// ---------- attention combine: R6 structure + eps prefetch pipeline ----------
__global__ __launch_bounds__(256) void attn_kernel(
    const float* __restrict__ lmu, const __bf16* __restrict__ lvar,
    const float* __restrict__ eps, __bf16* __restrict__ ah, __bf16* __restrict__ al)
{
  const int wid = threadIdx.x >> 6;
  const int lane = threadIdx.x & 63;
  const size_t r = (size_t)blockIdx.x * 4 + wid;
  const float* mrow = lmu + r * S_;
  const __bf16* vrow = lvar + r * S_;
  const int c0 = lane * 4;
  float mu[8], va[8], sd[8];
  {
    float4 m0 = *(const float4*)(mrow + c0);
    float4 m1 = *(const float4*)(mrow + 256 + c0);
    mu[0] = m0.x; mu[1] = m0.y; mu[2] = m0.z; mu[3] = m0.w;
    mu[4] = m1.x; mu[5] = m1.y; mu[6] = m1.z; mu[7] = m1.w;
    bf16x4 v0 = *(const bf16x4*)(vrow + c0);
    bf16x4 v1 = *(const bf16x4*)(vrow + 256 + c0);
#pragma unroll
    for (int i = 0; i < 4; ++i) { va[i] = (float)v0[i]; va[4 + i] = (float)v1[i]; }
  }
#pragma unroll
  for (int i = 0; i < 8; ++i) sd[i] = sqrtf(fmaxf(va[i], 1e-9f));
  // prefetch mc=0 eps BEFORE the serial top-k phase (loads in flight during it)
  float4 e0 = *(const float4*)(eps + r * S_ + c0);
  float4 e1 = *(const float4*)(eps + r * S_ + 256 + c0);
  // ---- top-8 by l_mu (tie-break: lowest index) ----
  unsigned sel = 0;
  float x[8];
#pragma unroll
  for (int i = 0; i < 8; ++i) x[i] = mu[i];
  for (int tsel = 0; tsel < 8; ++tsel) {
    float bv = -INFINITY; int bi = 0x7fffffff;
#pragma unroll
    for (int i = 0; i < 8; ++i) {
      int gi = (i < 4) ? (c0 + i) : (256 + c0 + i - 4);
      if (x[i] > bv || (x[i] == bv && gi < bi)) { bv = x[i]; bi = gi; }
    }
    for (int o = 32; o; o >>= 1) {
      float ov = __shfl_xor(bv, o); int oi = __shfl_xor(bi, o);
      if (ov > bv || (ov == bv && oi < bi)) { bv = ov; bi = oi; }
    }
    int half = bi >> 8;
    int rem = bi & 255;
    if ((rem >> 2) == lane) {
      int slot = (rem & 3) + 4 * half;
      sel |= 1u << slot;
      x[slot] = -INFINITY;
    }
  }
  // ---- MC-sample softmax mean (prefetch next sample before the reduce) ----
  float pacc[8] = {0, 0, 0, 0, 0, 0, 0, 0};
#pragma unroll
  for (int mc = 0; mc < MCK; ++mc) {
    float4 ce0 = e0, ce1 = e1;
    if (mc + 1 < MCK) {
      const float* np = eps + (size_t)(mc + 1) * BHSS_ + r * S_;
      e0 = *(const float4*)(np + c0);
      e1 = *(const float4*)(np + 256 + c0);
    }
    float xv[8];
    xv[0] = mu[0] + sd[0] * ce0.x; xv[1] = mu[1] + sd[1] * ce0.y;
    xv[2] = mu[2] + sd[2] * ce0.z; xv[3] = mu[3] + sd[3] * ce0.w;
    xv[4] = mu[4] + sd[4] * ce1.x; xv[5] = mu[5] + sd[5] * ce1.y;
    xv[6] = mu[6] + sd[6] * ce1.z; xv[7] = mu[7] + sd[7] * ce1.w;
    float m = -INFINITY;
#pragma unroll
    for (int i = 0; i < 8; ++i) m = fmaxf(m, xv[i]);
    m = wave_max(m);
    float e[8], zs = 0.f;
#pragma unroll
    for (int i = 0; i < 8; ++i) { e[i] = __expf(xv[i] - m); zs += e[i]; }
    zs = wave_sum(zs);
    float inv = 1.0f / zs;
#pragma unroll
    for (int i = 0; i < 8; ++i) pacc[i] += e[i] * inv;
  }
  // ---- rest (logit-normal) softmax with top-k excluded ----
  float adj[8];
#pragma unroll
  for (int i = 0; i < 8; ++i) {
    float a = mu[i] / sqrtf(1.0f + 0.39269908169872414f * va[i]);
    adj[i] = ((sel >> i) & 1u) ? -1e9f : a;
  }
  float m2 = -INFINITY;
#pragma unroll
  for (int i = 0; i < 8; ++i) m2 = fmaxf(m2, adj[i]);
  m2 = wave_max(m2);
  float e2[8], z2 = 0.f;
#pragma unroll
  for (int i = 0; i < 8; ++i) { e2[i] = __expf(adj[i] - m2); z2 += e2[i]; }
  z2 = wave_sum(z2);
  float inv2 = 1.0f / z2;
  float rest[8], tout[8], s = 0.f;
#pragma unroll
  for (int i = 0; i < 8; ++i) {
    rest[i] = e2[i] * inv2;
    tout[i] = ((sel >> i) & 1u) ? pacc[i] * 0.125f : rest[i];
    s += tout[i];
  }
  s = wave_sum(s);
  float rn = 1.0f / fmaxf(s, 1e-12f);
  bf16x4 oh0, oh1, ol0, ol1;
#pragma unroll
  for (int i = 0; i < 4; ++i) {
    float o = tout[i] * rn + rest[i];
    __bf16 h = (__bf16)o;
    oh0[i] = h; ol0[i] = (__bf16)(o - (float)h);
    float o1 = tout[4 + i] * rn + rest[4 + i];
    __bf16 h1 = (__bf16)o1;
    oh1[i] = h1; ol1[i] = (__bf16)(o1 - (float)h1);
  }
  *(bf16x4*)(ah + r * S_ + c0) = oh0;
  *(bf16x4*)(ah + r * S_ + 256 + c0) = oh1;
  *(bf16x4*)(al + r * S_ + c0) = ol0;
  *(bf16x4*)(al + r * S_ + 256 + c0) = ol1;
}

// ---------- PV (unchanged from R9): glds16 + swizzle + 2-phase dbuf ----------
#define PVBUF 10240
__global__ __launch_bounds__(256, 2) void pv_mfma(
    const __bf16* __restrict__ ah_, const __bf16* __restrict__ al_,
    const __bf16* __restrict__ vTh, const __bf16* __restrict__ vTl,
    const __bf16* __restrict__ vTv,
    __bf16* __restrict__ yh, __bf16* __restrict__ yl, __bf16* __restrict__ ys2)
{
  __shared__ __bf16 lds[2 * PVBUF];
  const int t = threadIdx.x;
  const int lane = t & 63, wid = t >> 6;
  const int wm = wid >> 1, wn = wid & 1;
  const int lin = blockIdx.x + 8 * blockIdx.y;
  const int xcd = lin & 7;
  const int rest = lin >> 3;
  const int q0 = (rest & 7) * 64;
  const int bh = xcd + 8 * (rest >> 3);
  const int b = bh >> 4, h = bh & 15;
  const __bf16* Ah = ah_ + (size_t)bh * S_ * S_;
  const __bf16* Al = al_ + (size_t)bh * S_ * S_;
  const __bf16* Vh = vTh + (size_t)bh * 64 * S_;
  const __bf16* Vl = vTl + (size_t)bh * 64 * S_;
  const __bf16* Vv = vTv + (size_t)bh * 64 * S_;
  int rA, sA; unswz(t, rA, sA);
  const size_t gAo = (size_t)(q0 + rA) * S_ + sA * 8;
  const size_t gVo = (size_t)rA * S_ + sA * 8;
  const int wofs = wid * 512;
  f32x4 accM[2][2] = {}; f32x4 accV[2][2] = {};
  const int fr = lane & 15, ks = lane >> 4;

  auto STAGE = [&](int buf, int k0) {
    __bf16* L = lds + buf * PVBUF;
    glds16(Ah + gAo + k0, L + 0    + wofs);
    glds16(Al + gAo + k0, L + 2048 + wofs);
    glds16(Vh + gVo + k0, L + 4096 + wofs);
    glds16(Vl + gVo + k0, L + 6144 + wofs);
    glds16(Vv + gVo + k0, L + 8192 + wofs);
  };

  STAGE(0, 0);
  for (int tt = 0; tt < 16; ++tt) {
    const int cur = tt & 1;
    if (tt < 15) {
      STAGE(cur ^ 1, (tt + 1) * 32);
      asm volatile("s_waitcnt vmcnt(5)" ::: "memory");
    } else {
      asm volatile("s_waitcnt vmcnt(0)" ::: "memory");
    }
    __builtin_amdgcn_s_barrier();
    __builtin_amdgcn_sched_barrier(0);
    const __bf16* L = lds + cur * PVBUF;
    bf16x8 fah[2], fal[2], fa2[2];
#pragma unroll
    for (int i = 0; i < 2; ++i) {
      int so = swz_el(wm * 32 + i * 16 + fr, ks);
      fah[i] = *(const bf16x8*)(L + 0 + so);
      fal[i] = *(const bf16x8*)(L + 2048 + so);
      fa2[i] = sq8(fah[i]);
    }
#pragma unroll
    for (int j = 0; j < 2; ++j) {
      int so = swz_el(wn * 32 + j * 16 + fr, ks);
      bf16x8 fvh = *(const bf16x8*)(L + 4096 + so);
      bf16x8 fvl = *(const bf16x8*)(L + 6144 + so);
      bf16x8 fvv = *(const bf16x8*)(L + 8192 + so);
#pragma unroll
      for (int i = 0; i < 2; ++i) {
        accM[i][j] = mfma16(fah[i], fvh, accM[i][j]);
        accM[i][j] = mfma16(fah[i], fvl, accM[i][j]);
        accM[i][j] = mfma16(fal[i], fvh, accM[i][j]);
        accV[i][j] = mfma16(fa2[i], fvv, accV[i][j]);
      }
    }
    __builtin_amdgcn_s_barrier();
  }
  const int fq = lane >> 4;
#pragma unroll
  for (int i = 0; i < 2; ++i)
#pragma unroll
    for (int j = 0; j < 2; ++j) {
      const int col = h * 64 + wn * 32 + j * 16 + fr;
      const int row0 = b * S_ + q0 + wm * 32 + i * 16 + fq * 4;
      f32x4 m_ = accM[i][j], v_ = accV[i][j];
#pragma unroll
      for (int r = 0; r < 4; ++r) {
        size_t off = (size_t)(row0 + r) * D_ + col;
        float mu = m_[r];
        __bf16 hh = (__bf16)mu;
        float ss = sqrtf(v_[r] + 1e-6f) + 1e-6f;
        yh[off] = hh;
        yl[off] = (__bf16)(mu - (float)hh);
        ys2[off] = (__bf16)(ss * ss);
      }
    }
}

extern "C" void kernel_launch(void* const* d_in, const int* in_sizes, int n_in,
                              void* d_out, int out_size, void* d_ws, size_t ws_size,
                              hipStream_t stream)
{
  const float* Qloc = (const float*)d_in[0];
  const float* Qsc  = (const float*)d_in[1];
  const float* Kloc = (const float*)d_in[2];
  const float* Ksc  = (const float*)d_in[3];
  const float* Vloc = (const float*)d_in[4];
  const float* Vsc  = (const float*)d_in[5];
  const float* Wq = (const float*)d_in[6];  const float* bq = (const float*)d_in[7];
  const float* Wk = (const float*)d_in[8];  const float* bk = (const float*)d_in[9];
  const float* Wv = (const float*)d_in[10]; const float* bv = (const float*)d_in[11];
  const float* Wo = (const float*)d_in[12]; const float* bo = (const float*)d_in[13];
  const float* tau = (const float*)d_in[14];
  const float* eps = (const float*)d_in[15];

  const size_t P = (size_t)MS * D_;
  const size_t DD = (size_t)D_ * D_;
  char* w = (char*)d_ws;
  auto carve = [&](size_t bytes) -> char* {
    char* p = w; w += (bytes + 255) & ~(size_t)255; return p;
  };
  __bf16* cQh = (__bf16*)carve(P * 2); __bf16* cQl = (__bf16*)carve(P * 2); __bf16* cQ2 = (__bf16*)carve(P * 2);
  __bf16* cKh = (__bf16*)carve(P * 2); __bf16* cKl = (__bf16*)carve(P * 2); __bf16* cK2 = (__bf16*)carve(P * 2);
  __bf16* cVh = (__bf16*)carve(P * 2); __bf16* cVl = (__bf16*)carve(P * 2); __bf16* cV2 = (__bf16*)carve(P * 2);
  __bf16* wqh = (__bf16*)carve(DD * 2); __bf16* wql = (__bf16*)carve(DD * 2);
  __bf16* wkh = (__bf16*)carve(DD * 2); __bf16* wkl = (__bf16*)carve(DD * 2);
  __bf16* wvh = (__bf16*)carve(DD * 2); __bf16* wvl = (__bf16*)carve(DD * 2);
  __bf16* woh = (__bf16*)carve(DD * 2); __bf16* wol = (__bf16*)carve(DD * 2);
  __bf16* qmh = (__bf16*)carve(P * 2); __bf16* qml = (__bf16*)carve(P * 2);
  __bf16* qm2 = (__bf16*)carve(P * 2); __bf16* qmv = (__bf16*)carve(P * 2);
  __bf16* kmh = (__bf16*)carve(P * 2); __bf16* kml = (__bf16*)carve(P * 2);
  __bf16* km2 = (__bf16*)carve(P * 2); __bf16* kmv = (__bf16*)carve(P * 2);
  __bf16* vTh = (__bf16*)carve(P * 2); __bf16* vTl = (__bf16*)carve(P * 2); __bf16* vTv = (__bf16*)carve(P * 2);
  float*  lmu = (float*)carve(BHSS_ * 4);
  __bf16* lvr = (__bf16*)carve(BHSS_ * 2);
  __bf16* ath = (__bf16*)carve(BHSS_ * 2);
  __bf16* atl = (__bf16*)carve(BHSS_ * 2);
  __bf16* yh = (__bf16*)carve(P * 2); __bf16* yl = (__bf16*)carve(P * 2); __bf16* ys2 = (__bf16*)carve(P * 2);
  float* out_loc = (float*)d_out;
  float* out_sc  = out_loc + P;

  dim3 blk(256);
  conv_all<<<5120, blk, 0, stream>>>(Qloc, Qsc, Kloc, Ksc, Vloc, Vsc,
                                     cQh, cQl, cQ2, cKh, cKl, cK2, cVh, cVl, cV2,
                                     Wq, Wk, Wv, Wo,
                                     wqh, wql, wkh, wkl, wvh, wvl, woh, wol);
  PArg3 pq;
  pq.a[0] = PArg{cQh, cQl, cQ2, wqh, wql, bq, qmh, qml, qm2, qmv, 0};
  pq.a[1] = PArg{cKh, cKl, cK2, wkh, wkl, bk, kmh, kml, km2, kmv, 0};
  pq.a[2] = PArg{cVh, cVl, cV2, wvh, wvl, bv, vTh, vTl, vTv, nullptr, 1};
  dgemm_qkv<<<dim3(8, 32, 3), blk, 0, stream>>>(pq);
  score_mfma<<<dim3(8, 8, 64), blk, 0, stream>>>(qmh, qml, qm2, qmv, kmh, kml, km2, kmv, lmu, lvr, tau);
  attn_kernel<<<dim3((unsigned)(BHS_ / 4)), blk, 0, stream>>>(lmu, lvr, eps, ath, atl);
  pv_mfma<<<dim3(8, 64), blk, 0, stream>>>(ath, atl, vTh, vTl, vTv, yh, yl, ys2);
  dgemm_o<<<dim3(8, 32), blk, 0, stream>>>(yh, yl, ys2, woh, wol, bo, out_loc, out_sc);
}

// Round 11
// 342.526 us; speedup vs baseline: 1.0177x; 1.0177x over previous
//
#include <hip/hip_runtime.h>
#include <math.h>

#define B_ 4
#define S_ 512
#define D_ 1024
#define H_ 16
#define MCK 8
#define MS 2048
#define BHSS_ ((size_t)16777216)   // B*H*S*S
#define BHS_  ((size_t)32768)

typedef __attribute__((ext_vector_type(8))) __bf16 bf16x8;
typedef __attribute__((ext_vector_type(4))) __bf16 bf16x4;
typedef __attribute__((ext_vector_type(4))) float f32x4;

__device__ __forceinline__ f32x4 mfma16(bf16x8 a, bf16x8 b, f32x4 c) {
  return __builtin_amdgcn_mfma_f32_16x16x32_bf16(a, b, c, 0, 0, 0);
}
__device__ __forceinline__ bf16x8 sq8(bf16x8 x) {
  bf16x8 r;
#pragma unroll
  for (int i = 0; i < 8; ++i) { float f = (float)x[i]; r[i] = (__bf16)(f * f); }
  return r;
}
// (Wh+Wl)^2 elementwise -> bf16
__device__ __forceinline__ bf16x8 sq8s(bf16x8 h, bf16x8 l) {
  bf16x8 r;
#pragma unroll
  for (int i = 0; i < 8; ++i) { float f = (float)h[i] + (float)l[i]; r[i] = (__bf16)(f * f); }
  return r;
}
__device__ __forceinline__ float wave_max(float v) {
#pragma unroll
  for (int o = 32; o; o >>= 1) v = fmaxf(v, __shfl_xor(v, o));
  return v;
}
__device__ __forceinline__ float wave_sum(float v) {
#pragma unroll
  for (int o = 32; o; o >>= 1) v += __shfl_xor(v, o);
  return v;
}

// ---- LDS swizzle helpers: [rows][32] tiles (4 slots of 16B per row) ----
__device__ __forceinline__ void unswz(int u, int& row, int& slot) {
  int row0 = ((u >> 2) ^ (u >> 4)) & 1;
  row = ((u >> 3) << 1) | row0;
  int s0 = (u ^ (u >> 2) ^ (u >> 4)) & 1;
  int s1 = ((u >> 1) ^ (u >> 3)) & 1;
  slot = (s1 << 1) | s0;
}
__device__ __forceinline__ int swz_el(int row, int slot) {
  return ((row * 4 + slot) ^ (row & 7)) * 8;
}
// ---- [rows][64] tiles (8 slots of 16B per row): L = (row*8+slot)^(row&7) ----
__device__ __forceinline__ int swz8_el(int row, int slot) {
  return ((row * 8 + slot) ^ (row & 7)) * 8;
}
__device__ __forceinline__ void unswz8(int u, int& row, int& slot) {
  row = u >> 3;
  slot = (u & 7) ^ (row & 7);
}
__device__ __forceinline__ void glds16(const void* gsrc, void* ldst) {
  __builtin_amdgcn_global_load_lds(
      (const __attribute__((address_space(1))) void*)gsrc,
      (__attribute__((address_space(3))) void*)ldst, 16, 0, 0);
}

// ---------- fused conversion: inputs (loc,scale)->(hi,lo,scale^2); weights W->(hi,lo) ----
__global__ __launch_bounds__(256) void conv_all(
    const float* __restrict__ l0, const float* __restrict__ s0,
    const float* __restrict__ l1, const float* __restrict__ s1,
    const float* __restrict__ l2, const float* __restrict__ s2,
    __bf16* h0, __bf16* o0, __bf16* v0,
    __bf16* h1, __bf16* o1, __bf16* v1,
    __bf16* h2, __bf16* o2, __bf16* v2,
    const float* __restrict__ w0, const float* __restrict__ w1,
    const float* __restrict__ w2, const float* __restrict__ w3,
    __bf16* wh0, __bf16* wo0, __bf16* wh1, __bf16* wo1,
    __bf16* wh2, __bf16* wo2, __bf16* wh3, __bf16* wo3)
{
  const int bid = blockIdx.x;
  if (bid < 3072) {
    const int tn = bid >> 10;
    const size_t i0 = ((size_t)(bid & 1023) * 256 + threadIdx.x) * 8;
    const float* L = tn == 0 ? l0 : tn == 1 ? l1 : l2;
    const float* S = tn == 0 ? s0 : tn == 1 ? s1 : s2;
    __bf16* Hh = tn == 0 ? h0 : tn == 1 ? h1 : h2;
    __bf16* Lo = tn == 0 ? o0 : tn == 1 ? o1 : o2;
    __bf16* V2 = tn == 0 ? v0 : tn == 1 ? v1 : v2;
    float4 x0 = *(const float4*)(L + i0), x1 = *(const float4*)(L + i0 + 4);
    float4 y0 = *(const float4*)(S + i0), y1 = *(const float4*)(S + i0 + 4);
    float xs[8] = {x0.x, x0.y, x0.z, x0.w, x1.x, x1.y, x1.z, x1.w};
    float ys[8] = {y0.x, y0.y, y0.z, y0.w, y1.x, y1.y, y1.z, y1.w};
    bf16x8 hh, ll, vv;
#pragma unroll
    for (int i = 0; i < 8; ++i) {
      __bf16 h = (__bf16)xs[i];
      hh[i] = h;
      ll[i] = (__bf16)(xs[i] - (float)h);
      vv[i] = (__bf16)(ys[i] * ys[i]);
    }
    *(bf16x8*)(Hh + i0) = hh;
    *(bf16x8*)(Lo + i0) = ll;
    *(bf16x8*)(V2 + i0) = vv;
  } else {
    const int b2 = bid - 3072;
    const int tn = b2 >> 9;
    const size_t i0 = ((size_t)(b2 & 511) * 256 + threadIdx.x) * 8;
    const float* W = tn == 0 ? w0 : tn == 1 ? w1 : tn == 2 ? w2 : w3;
    __bf16* Hh = tn == 0 ? wh0 : tn == 1 ? wh1 : tn == 2 ? wh2 : wh3;
    __bf16* Lo = tn == 0 ? wo0 : tn == 1 ? wo1 : tn == 2 ? wo2 : wo3;
    float4 x0 = *(const float4*)(W + i0), x1 = *(const float4*)(W + i0 + 4);
    float xs[8] = {x0.x, x0.y, x0.z, x0.w, x1.x, x1.y, x1.z, x1.w};
    bf16x8 hh, ll;
#pragma unroll
    for (int i = 0; i < 8; ++i) {
      __bf16 h = (__bf16)xs[i];
      hh[i] = h;
      ll[i] = (__bf16)(xs[i] - (float)h);
    }
    *(bf16x8*)(Hh + i0) = hh;
    *(bf16x8*)(Lo + i0) = ll;
  }
}

// ---------- batched dual-GEMM projection (unchanged from R6) ----------
struct PArg {
  const __bf16 *Ah, *Al, *A2, *Wh, *Wl;
  const float* bias;
  __bf16 *P0, *P1, *P2, *P3;
  int epi;
};
struct PArg3 { PArg a[3]; };

#define LDSBUF 14336

__global__ __launch_bounds__(256, 2) void dgemm_qkv(PArg3 P3v)
{
  __shared__ __bf16 lds[2 * LDSBUF];
  const int lin = blockIdx.x + 8 * blockIdx.y + 256 * blockIdx.z;
  const int xcd = lin & 7;
  const int rest = lin >> 3;
  const int mi   = rest & 3;
  const int nblk = (rest >> 2) & 7;
  const int proj = rest >> 5;
  const PArg p = P3v.a[proj];
  const int m0 = (xcd + 8 * mi) * 64;
  const int n0 = nblk * 128;
  const int t = threadIdx.x, lane = t & 63, wid = t >> 6;
  int rA, sA; unswz(t, rA, sA);
  const size_t gA = (size_t)(m0 + rA) * D_ + sA * 8;
  const size_t gW0 = (size_t)(n0 + rA) * D_ + sA * 8;
  int rW1, sW1; unswz(t + 256, rW1, sW1);
  const size_t gW1 = (size_t)(n0 + rW1) * D_ + sW1 * 8;
  const int wofs = wid * 512;
  f32x4 accM[4][2] = {}; f32x4 accV[4][2] = {};
  const int fr = lane & 15, ks = lane >> 4;

  auto STAGE = [&](int buf, int k0) {
    __bf16* L = lds + buf * LDSBUF;
    glds16(p.Ah + gA + k0,  L + 0     + wofs);
    glds16(p.Al + gA + k0,  L + 2048  + wofs);
    glds16(p.A2 + gA + k0,  L + 4096  + wofs);
    glds16(p.Wh + gW0 + k0, L + 6144  + wofs);
    glds16(p.Wl + gW0 + k0, L + 10240 + wofs);
    glds16(p.Wh + gW1 + k0, L + 6144 + 2048 + wofs);
    glds16(p.Wl + gW1 + k0, L + 10240 + 2048 + wofs);
  };

  STAGE(0, 0);
  for (int tt = 0; tt < 32; ++tt) {
    const int cur = tt & 1;
    if (tt < 31) {
      STAGE(cur ^ 1, (tt + 1) * 32);
      asm volatile("s_waitcnt vmcnt(7)" ::: "memory");
    } else {
      asm volatile("s_waitcnt vmcnt(0)" ::: "memory");
    }
    __builtin_amdgcn_s_barrier();
    __builtin_amdgcn_sched_barrier(0);
    const __bf16* L = lds + cur * LDSBUF;
    bf16x8 fah[4], fal[4], fa2[4];
#pragma unroll
    for (int i = 0; i < 4; ++i) {
      int so = swz_el(i * 16 + fr, ks);
      fah[i] = *(const bf16x8*)(L + 0 + so);
      fal[i] = *(const bf16x8*)(L + 2048 + so);
      fa2[i] = *(const bf16x8*)(L + 4096 + so);
    }
#pragma unroll
    for (int j = 0; j < 2; ++j) {
      int so = swz_el(wid * 32 + j * 16 + fr, ks);
      bf16x8 fwh = *(const bf16x8*)(L + 6144 + so);
      bf16x8 fwl = *(const bf16x8*)(L + 10240 + so);
      bf16x8 fw2 = sq8s(fwh, fwl);
#pragma unroll
      for (int i = 0; i < 4; ++i) {
        accM[i][j] = mfma16(fah[i], fwh, accM[i][j]);
        accM[i][j] = mfma16(fah[i], fwl, accM[i][j]);
        accM[i][j] = mfma16(fal[i], fwh, accM[i][j]);
        accV[i][j] = mfma16(fa2[i], fw2, accV[i][j]);
      }
    }
    __builtin_amdgcn_s_barrier();
  }
  const int fq = lane >> 4;
#pragma unroll
  for (int j = 0; j < 2; ++j) {
    const int col = n0 + wid * 32 + j * 16 + fr;
    const float bcol = p.bias[col];
#pragma unroll
    for (int i = 0; i < 4; ++i) {
      const int row0 = m0 + i * 16 + fq * 4;
      f32x4 m_ = accM[i][j], v_ = accV[i][j];
      if (p.epi == 0) {
#pragma unroll
        for (int r = 0; r < 4; ++r) {
          size_t off = (size_t)(row0 + r) * D_ + col;
          float mu = m_[r] + bcol;
          __bf16 h = (__bf16)mu;
          float s = sqrtf(v_[r]) + 1e-6f;
          p.P0[off] = h;
          p.P1[off] = (__bf16)(mu - (float)h);
          p.P2[off] = (__bf16)(mu * mu);
          p.P3[off] = (__bf16)(s * s);
        }
      } else {
        const int b = row0 >> 9, ss0 = row0 & 511;
        const int hh = col >> 6, dd = col & 63;
        size_t base = ((size_t)(b * H_ + hh) * 64 + dd) * S_ + ss0;
        bf16x4 vh, vl, vq;
#pragma unroll
        for (int r = 0; r < 4; ++r) {
          float mu = m_[r] + bcol;
          __bf16 h = (__bf16)mu;
          vh[r] = h;
          vl[r] = (__bf16)(mu - (float)h);
          float s = sqrtf(v_[r]) + 1e-6f;
          vq[r] = (__bf16)(s * s);
        }
        *(bf16x4*)(p.P0 + base) = vh;
        *(bf16x4*)(p.P1 + base) = vl;
        *(bf16x4*)(p.P2 + base) = vq;
      }
    }
  }
}

// ---------- output projection (unchanged from R6) ----------
__global__ __launch_bounds__(256, 2) void dgemm_o(
    const __bf16* __restrict__ Ah, const __bf16* __restrict__ Al, const __bf16* __restrict__ A2,
    const __bf16* __restrict__ Wh, const __bf16* __restrict__ Wl,
    const float* __restrict__ bias, float* __restrict__ O0, float* __restrict__ O1)
{
  __shared__ __bf16 lds[2 * LDSBUF];
  const int lin = blockIdx.x + 8 * blockIdx.y;
  const int xcd = lin & 7;
  const int rest = lin >> 3;
  const int mi   = rest & 3;
  const int nblk = rest >> 2;
  const int m0 = (xcd + 8 * mi) * 64;
  const int n0 = nblk * 128;
  const int t = threadIdx.x, lane = t & 63, wid = t >> 6;
  int rA, sA; unswz(t, rA, sA);
  const size_t gA = (size_t)(m0 + rA) * D_ + sA * 8;
  const size_t gW0 = (size_t)(n0 + rA) * D_ + sA * 8;
  int rW1, sW1; unswz(t + 256, rW1, sW1);
  const size_t gW1 = (size_t)(n0 + rW1) * D_ + sW1 * 8;
  const int wofs = wid * 512;
  f32x4 accM[4][2] = {}; f32x4 accV[4][2] = {};
  const int fr = lane & 15, ks = lane >> 4;

  auto STAGE = [&](int buf, int k0) {
    __bf16* L = lds + buf * LDSBUF;
    glds16(Ah + gA + k0,  L + 0     + wofs);
    glds16(Al + gA + k0,  L + 2048  + wofs);
    glds16(A2 + gA + k0,  L + 4096  + wofs);
    glds16(Wh + gW0 + k0, L + 6144  + wofs);
    glds16(Wl + gW0 + k0, L + 10240 + wofs);
    glds16(Wh + gW1 + k0, L + 6144 + 2048 + wofs);
    glds16(Wl + gW1 + k0, L + 10240 + 2048 + wofs);
  };

  STAGE(0, 0);
  for (int tt = 0; tt < 32; ++tt) {
    const int cur = tt & 1;
    if (tt < 31) {
      STAGE(cur ^ 1, (tt + 1) * 32);
      asm volatile("s_waitcnt vmcnt(7)" ::: "memory");
    } else {
      asm volatile("s_waitcnt vmcnt(0)" ::: "memory");
    }
    __builtin_amdgcn_s_barrier();
    __builtin_amdgcn_sched_barrier(0);
    const __bf16* L = lds + cur * LDSBUF;
    bf16x8 fah[4], fal[4], fa2[4];
#pragma unroll
    for (int i = 0; i < 4; ++i) {
      int so = swz_el(i * 16 + fr, ks);
      fah[i] = *(const bf16x8*)(L + 0 + so);
      fal[i] = *(const bf16x8*)(L + 2048 + so);
      fa2[i] = *(const bf16x8*)(L + 4096 + so);
    }
#pragma unroll
    for (int j = 0; j < 2; ++j) {
      int so = swz_el(wid * 32 + j * 16 + fr, ks);
      bf16x8 fwh = *(const bf16x8*)(L + 6144 + so);
      bf16x8 fwl = *(const bf16x8*)(L + 10240 + so);
      bf16x8 fw2 = sq8s(fwh, fwl);
#pragma unroll
      for (int i = 0; i < 4; ++i) {
        accM[i][j] = mfma16(fah[i], fwh, accM[i][j]);
        accM[i][j] = mfma16(fah[i], fwl, accM[i][j]);
        accM[i][j] = mfma16(fal[i], fwh, accM[i][j]);
        accV[i][j] = mfma16(fa2[i], fw2, accV[i][j]);
      }
    }
    __builtin_amdgcn_s_barrier();
  }
  const int fq = lane >> 4;
#pragma unroll
  for (int j = 0; j < 2; ++j) {
    const int col = n0 + wid * 32 + j * 16 + fr;
    const float bcol = bias[col];
#pragma unroll
    for (int i = 0; i < 4; ++i) {
      const int row0 = m0 + i * 16 + fq * 4;
      f32x4 m_ = accM[i][j], v_ = accV[i][j];
#pragma unroll
      for (int r = 0; r < 4; ++r) {
        size_t off = (size_t)(row0 + r) * D_ + col;
        O0[off] = m_[r] + bcol;
        O1[off] = sqrtf(v_[r]);
      }
    }
  }
}

// ---------- score (unchanged from R9): glds16 single-shot + swizzled reads ----------
__global__ __launch_bounds__(256, 2) void score_mfma(
    const __bf16* __restrict__ qh, const __bf16* __restrict__ ql,
    const __bf16* __restrict__ q2, const __bf16* __restrict__ qv,
    const __bf16* __restrict__ kh, const __bf16* __restrict__ kl,
    const __bf16* __restrict__ k2, const __bf16* __restrict__ kv,
    float* __restrict__ lmu, __bf16* __restrict__ lvar,
    const float* __restrict__ taup)
{
  __shared__ __bf16 S[32768];
  const int t = threadIdx.x;
  const int lane = t & 63, wid = t >> 6;
  const int wm = wid >> 1, wn = wid & 1;
  const int lin = blockIdx.x + 8 * blockIdx.y + 64 * blockIdx.z;
  const int xcd = lin & 7;
  const int rest = lin >> 3;
  const int tile = rest & 63;
  const int bh = xcd + 8 * (rest >> 6);
  const int kk0 = (tile & 7) * 64, q0 = (tile >> 3) * 64;
  const int b = bh >> 4, h = bh & 15;
  const size_t hb = ((size_t)b * S_) * D_ + (size_t)h * 64;
  {
    int r0, s0, r1, s1;
    unswz8(t, r0, s0);
    unswz8(t + 256, r1, s1);
    const __bf16* qa[4] = {qh, ql, q2, qv};
    const __bf16* ka[4] = {kh, kl, k2, kv};
    const int wofs = wid * 512;
#pragma unroll
    for (int a = 0; a < 4; ++a) {
      glds16(qa[a] + hb + (size_t)(q0 + r0) * D_ + s0 * 8, S + a * 4096 + wofs);
      glds16(qa[a] + hb + (size_t)(q0 + r1) * D_ + s1 * 8, S + a * 4096 + 2048 + wofs);
      glds16(ka[a] + hb + (size_t)(kk0 + r0) * D_ + s0 * 8, S + 16384 + a * 4096 + wofs);
      glds16(ka[a] + hb + (size_t)(kk0 + r1) * D_ + s1 * 8, S + 16384 + a * 4096 + 2048 + wofs);
    }
  }
  asm volatile("s_waitcnt vmcnt(0)" ::: "memory");
  __builtin_amdgcn_s_barrier();
  __builtin_amdgcn_sched_barrier(0);

  f32x4 accM[2][2] = {}; f32x4 accV[2][2] = {};
  const int fr = lane & 15, fq = lane >> 4;
#pragma unroll
  for (int ds = 0; ds < 2; ++ds) {
    const int slot = ds * 4 + fq;
    bf16x8 fqh_[2], fql_[2], fq2_[2], fqv_[2];
#pragma unroll
    for (int i = 0; i < 2; ++i) {
      int off = swz8_el(wm * 32 + i * 16 + fr, slot);
      fqh_[i] = *(const bf16x8*)(S + 0 * 4096 + off);
      fql_[i] = *(const bf16x8*)(S + 1 * 4096 + off);
      fq2_[i] = *(const bf16x8*)(S + 2 * 4096 + off);
      fqv_[i] = *(const bf16x8*)(S + 3 * 4096 + off);
    }
#pragma unroll
    for (int j = 0; j < 2; ++j) {
      int koff = swz8_el(wn * 32 + j * 16 + fr, slot);
      bf16x8 fkh_ = *(const bf16x8*)(S + 16384 + 0 * 4096 + koff);
      bf16x8 fkl_ = *(const bf16x8*)(S + 16384 + 1 * 4096 + koff);
      bf16x8 fk2_ = *(const bf16x8*)(S + 16384 + 2 * 4096 + koff);
      bf16x8 fkv_ = *(const bf16x8*)(S + 16384 + 3 * 4096 + koff);
#pragma unroll
      for (int i = 0; i < 2; ++i) {
        accM[i][j] = mfma16(fqh_[i], fkh_, accM[i][j]);
        accM[i][j] = mfma16(fqh_[i], fkl_, accM[i][j]);
        accM[i][j] = mfma16(fql_[i], fkh_, accM[i][j]);
        accV[i][j] = mfma16(fq2_[i], fkv_, accV[i][j]);
        accV[i][j] = mfma16(fqv_[i], fk2_, accV[i][j]);
        accV[i][j] = mfma16(fqv_[i], fkv_, accV[i][j]);
      }
    }
  }
  const float itau = 1.0f / *taup;
#pragma unroll
  for (int i = 0; i < 2; ++i)
#pragma unroll
    for (int j = 0; j < 2; ++j) {
      const int col = kk0 + wn * 32 + j * 16 + fr;
      const int row0 = q0 + wm * 32 + i * 16 + fq * 4;
      f32x4 m_ = accM[i][j], v_ = accV[i][j];
#pragma unroll
      for (int r = 0; r < 4; ++r) {
        size_t off = ((size_t)bh * S_ + row0 + r) * S_ + col;
        lmu[off] = m_[r] * 0.125f * itau;
        float lv = ((v_[r] + 1e-6f) * (1.0f / 64.0f) + 1e-6f) * itau * itau + 1e-6f;
        lvar[off] = (__bf16)lv;
      }
    }
}

// ---------- attention combine (exact R6 version) ----------
__global__ __launch_bounds__(256) void attn_kernel(
    const float* __restrict__ lmu, const __bf16* __restrict__ lvar,
    const float* __restrict__ eps, __bf16* __restrict__ ah, __bf16* __restrict__ al)
{
  const int wid = threadIdx.x >> 6;
  const int lane = threadIdx.x & 63;
  const size_t r = (size_t)blockIdx.x * 4 + wid;
  const float* mrow = lmu + r * S_;
  const __bf16* vrow = lvar + r * S_;
  const int c0 = lane * 4;
  float mu[8], va[8], sd[8];
  {
    float4 m0 = *(const float4*)(mrow + c0);
    float4 m1 = *(const float4*)(mrow + 256 + c0);
    mu[0] = m0.x; mu[1] = m0.y; mu[2] = m0.z; mu[3] = m0.w;
    mu[4] = m1.x; mu[5] = m1.y; mu[6] = m1.z; mu[7] = m1.w;
    bf16x4 v0 = *(const bf16x4*)(vrow + c0);
    bf16x4 v1 = *(const bf16x4*)(vrow + 256 + c0);
#pragma unroll
    for (int i = 0; i < 4; ++i) { va[i] = (float)v0[i]; va[4 + i] = (float)v1[i]; }
  }
#pragma unroll
  for (int i = 0; i < 8; ++i) sd[i] = sqrtf(fmaxf(va[i], 1e-9f));
  unsigned sel = 0;
  float x[8];
#pragma unroll
  for (int i = 0; i < 8; ++i) x[i] = mu[i];
  for (int tsel = 0; tsel < 8; ++tsel) {
    float bv = -INFINITY; int bi = 0x7fffffff;
#pragma unroll
    for (int i = 0; i < 8; ++i) {
      int gi = (i < 4) ? (c0 + i) : (256 + c0 + i - 4);
      if (x[i] > bv || (x[i] == bv && gi < bi)) { bv = x[i]; bi = gi; }
    }
    for (int o = 32; o; o >>= 1) {
      float ov = __shfl_xor(bv, o); int oi = __shfl_xor(bi, o);
      if (ov > bv || (ov == bv && oi < bi)) { bv = ov; bi = oi; }
    }
    int half = bi >> 8;
    int rem = bi & 255;
    if ((rem >> 2) == lane) {
      int slot = (rem & 3) + 4 * half;
      sel |= 1u << slot;
      x[slot] = -INFINITY;
    }
  }
  float pacc[8] = {0, 0, 0, 0, 0, 0, 0, 0};
  for (int mc = 0; mc < MCK; ++mc) {
    const float* ep = eps + (size_t)mc * BHSS_ + r * S_;
    float4 e0 = *(const float4*)(ep + c0);
    float4 e1 = *(const float4*)(ep + 256 + c0);
    float xv[8];
    xv[0] = mu[0] + sd[0] * e0.x; xv[1] = mu[1] + sd[1] * e0.y;
    xv[2] = mu[2] + sd[2] * e0.z; xv[3] = mu[3] + sd[3] * e0.w;
    xv[4] = mu[4] + sd[4] * e1.x; xv[5] = mu[5] + sd[5] * e1.y;
    xv[6] = mu[6] + sd[6] * e1.z; xv[7] = mu[7] + sd[7] * e1.w;
    float m = -INFINITY;
#pragma unroll
    for (int i = 0; i < 8; ++i) m = fmaxf(m, xv[i]);
    m = wave_max(m);
    float e[8], zs = 0.f;
#pragma unroll
    for (int i = 0; i < 8; ++i) { e[i] = __expf(xv[i] - m); zs += e[i]; }
    zs = wave_sum(zs);
    float inv = 1.0f / zs;
#pragma unroll
    for (int i = 0; i < 8; ++i) pacc[i] += e[i] * inv;
  }
  float adj[8];
#pragma unroll
  for (int i = 0; i < 8; ++i) {
    float a = mu[i] / sqrtf(1.0f + 0.39269908169872414f * va[i]);
    adj[i] = ((sel >> i) & 1u) ? -1e9f : a;
  }
  float m2 = -INFINITY;
#pragma unroll
  for (int i = 0; i < 8; ++i) m2 = fmaxf(m2, adj[i]);
  m2 = wave_max(m2);
  float e2[8], z2 = 0.f;
#pragma unroll
  for (int i = 0; i < 8; ++i) { e2[i] = __expf(adj[i] - m2); z2 += e2[i]; }
  z2 = wave_sum(z2);
  float inv2 = 1.0f / z2;
  float rest[8], tout[8], s = 0.f;
#pragma unroll
  for (int i = 0; i < 8; ++i) {
    rest[i] = e2[i] * inv2;
    tout[i] = ((sel >> i) & 1u) ? pacc[i] * 0.125f : rest[i];
    s += tout[i];
  }
  s = wave_sum(s);
  float rn = 1.0f / fmaxf(s, 1e-12f);
  bf16x4 oh0, oh1, ol0, ol1;
#pragma unroll
  for (int i = 0; i < 4; ++i) {
    float o = tout[i] * rn + rest[i];
    __bf16 h = (__bf16)o;
    oh0[i] = h; ol0[i] = (__bf16)(o - (float)h);
    float o1 = tout[4 + i] * rn + rest[4 + i];
    __bf16 h1 = (__bf16)o1;
    oh1[i] = h1; ol1[i] = (__bf16)(o1 - (float)h1);
  }
  *(bf16x4*)(ah + r * S_ + c0) = oh0;
  *(bf16x4*)(ah + r * S_ + 256 + c0) = oh1;
  *(bf16x4*)(al + r * S_ + c0) = ol0;
  *(bf16x4*)(al + r * S_ + 256 + c0) = ol1;
}

// ---------- PV (unchanged from R9): glds16 + swizzle + 2-phase dbuf ----------
#define PVBUF 10240
__global__ __launch_bounds__(256, 2) void pv_mfma(
    const __bf16* __restrict__ ah_, const __bf16* __restrict__ al_,
    const __bf16* __restrict__ vTh, const __bf16* __restrict__ vTl,
    const __bf16* __restrict__ vTv,
    __bf16* __restrict__ yh, __bf16* __restrict__ yl, __bf16* __restrict__ ys2)
{
  __shared__ __bf16 lds[2 * PVBUF];
  const int t = threadIdx.x;
  const int lane = t & 63, wid = t >> 6;
  const int wm = wid >> 1, wn = wid & 1;
  const int lin = blockIdx.x + 8 * blockIdx.y;
  const int xcd = lin & 7;
  const int rest = lin >> 3;
  const int q0 = (rest & 7) * 64;
  const int bh = xcd + 8 * (rest >> 3);
  const int b = bh >> 4, h = bh & 15;
  const __bf16* Ah = ah_ + (size_t)bh * S_ * S_;
  const __bf16* Al = al_ + (size_t)bh * S_ * S_;
  const __bf16* Vh = vTh + (size_t)bh * 64 * S_;
  const __bf16* Vl = vTl + (size_t)bh * 64 * S_;
  const __bf16* Vv = vTv + (size_t)bh * 64 * S_;
  int rA, sA; unswz(t, rA, sA);
  const size_t gAo = (size_t)(q0 + rA) * S_ + sA * 8;
  const size_t gVo = (size_t)rA * S_ + sA * 8;
  const int wofs = wid * 512;
  f32x4 accM[2][2] = {}; f32x4 accV[2][2] = {};
  const int fr = lane & 15, ks = lane >> 4;

  auto STAGE = [&](int buf, int k0) {
    __bf16* L = lds + buf * PVBUF;
    glds16(Ah + gAo + k0, L + 0    + wofs);
    glds16(Al + gAo + k0, L + 2048 + wofs);
    glds16(Vh + gVo + k0, L + 4096 + wofs);
    glds16(Vl + gVo + k0, L + 6144 + wofs);
    glds16(Vv + gVo + k0, L + 8192 + wofs);
  };

  STAGE(0, 0);
  for (int tt = 0; tt < 16; ++tt) {
    const int cur = tt & 1;
    if (tt < 15) {
      STAGE(cur ^ 1, (tt + 1) * 32);
      asm volatile("s_waitcnt vmcnt(5)" ::: "memory");
    } else {
      asm volatile("s_waitcnt vmcnt(0)" ::: "memory");
    }
    __builtin_amdgcn_s_barrier();
    __builtin_amdgcn_sched_barrier(0);
    const __bf16* L = lds + cur * PVBUF;
    bf16x8 fah[2], fal[2], fa2[2];
#pragma unroll
    for (int i = 0; i < 2; ++i) {
      int so = swz_el(wm * 32 + i * 16 + fr, ks);
      fah[i] = *(const bf16x8*)(L + 0 + so);
      fal[i] = *(const bf16x8*)(L + 2048 + so);
      fa2[i] = sq8(fah[i]);
    }
#pragma unroll
    for (int j = 0; j < 2; ++j) {
      int so = swz_el(wn * 32 + j * 16 + fr, ks);
      bf16x8 fvh = *(const bf16x8*)(L + 4096 + so);
      bf16x8 fvl = *(const bf16x8*)(L + 6144 + so);
      bf16x8 fvv = *(const bf16x8*)(L + 8192 + so);
#pragma unroll
      for (int i = 0; i < 2; ++i) {
        accM[i][j] = mfma16(fah[i], fvh, accM[i][j]);
        accM[i][j] = mfma16(fah[i], fvl, accM[i][j]);
        accM[i][j] = mfma16(fal[i], fvh, accM[i][j]);
        accV[i][j] = mfma16(fa2[i], fvv, accV[i][j]);
      }
    }
    __builtin_amdgcn_s_barrier();
  }
  const int fq = lane >> 4;
#pragma unroll
  for (int i = 0; i < 2; ++i)
#pragma unroll
    for (int j = 0; j < 2; ++j) {
      const int col = h * 64 + wn * 32 + j * 16 + fr;
      const int row0 = b * S_ + q0 + wm * 32 + i * 16 + fq * 4;
      f32x4 m_ = accM[i][j], v_ = accV[i][j];
#pragma unroll
      for (int r = 0; r < 4; ++r) {
        size_t off = (size_t)(row0 + r) * D_ + col;
        float mu = m_[r];
        __bf16 hh = (__bf16)mu;
        float ss = sqrtf(v_[r] + 1e-6f) + 1e-6f;
        yh[off] = hh;
        yl[off] = (__bf16)(mu - (float)hh);
        ys2[off] = (__bf16)(ss * ss);
      }
    }
}

extern "C" void kernel_launch(void* const* d_in, const int* in_sizes, int n_in,
                              void* d_out, int out_size, void* d_ws, size_t ws_size,
                              hipStream_t stream)
{
  const float* Qloc = (const float*)d_in[0];
  const float* Qsc  = (const float*)d_in[1];
  const float* Kloc = (const float*)d_in[2];
  const float* Ksc  = (const float*)d_in[3];
  const float* Vloc = (const float*)d_in[4];
  const float* Vsc  = (const float*)d_in[5];
  const float* Wq = (const float*)d_in[6];  const float* bq = (const float*)d_in[7];
  const float* Wk = (const float*)d_in[8];  const float* bk = (const float*)d_in[9];
  const float* Wv = (const float*)d_in[10]; const float* bv = (const float*)d_in[11];
  const float* Wo = (const float*)d_in[12]; const float* bo = (const float*)d_in[13];
  const float* tau = (const float*)d_in[14];
  const float* eps = (const float*)d_in[15];

  const size_t P = (size_t)MS * D_;
  const size_t DD = (size_t)D_ * D_;
  char* w = (char*)d_ws;
  auto carve = [&](size_t bytes) -> char* {
    char* p = w; w += (bytes + 255) & ~(size_t)255; return p;
  };
  __bf16* cQh = (__bf16*)carve(P * 2); __bf16* cQl = (__bf16*)carve(P * 2); __bf16* cQ2 = (__bf16*)carve(P * 2);
  __bf16* cKh = (__bf16*)carve(P * 2); __bf16* cKl = (__bf16*)carve(P * 2); __bf16* cK2 = (__bf16*)carve(P * 2);
  __bf16* cVh = (__bf16*)carve(P * 2); __bf16* cVl = (__bf16*)carve(P * 2); __bf16* cV2 = (__bf16*)carve(P * 2);
  __bf16* wqh = (__bf16*)carve(DD * 2); __bf16* wql = (__bf16*)carve(DD * 2);
  __bf16* wkh = (__bf16*)carve(DD * 2); __bf16* wkl = (__bf16*)carve(DD * 2);
  __bf16* wvh = (__bf16*)carve(DD * 2); __bf16* wvl = (__bf16*)carve(DD * 2);
  __bf16* woh = (__bf16*)carve(DD * 2); __bf16* wol = (__bf16*)carve(DD * 2);
  __bf16* qmh = (__bf16*)carve(P * 2); __bf16* qml = (__bf16*)carve(P * 2);
  __bf16* qm2 = (__bf16*)carve(P * 2); __bf16* qmv = (__bf16*)carve(P * 2);
  __bf16* kmh = (__bf16*)carve(P * 2); __bf16* kml = (__bf16*)carve(P * 2);
  __bf16* km2 = (__bf16*)carve(P * 2); __bf16* kmv = (__bf16*)carve(P * 2);
  __bf16* vTh = (__bf16*)carve(P * 2); __bf16* vTl = (__bf16*)carve(P * 2); __bf16* vTv = (__bf16*)carve(P * 2);
  float*  lmu = (float*)carve(BHSS_ * 4);
  __bf16* lvr = (__bf16*)carve(BHSS_ * 2);
  __bf16* ath = (__bf16*)carve(BHSS_ * 2);
  __bf16* atl = (__bf16*)carve(BHSS_ * 2);
  __bf16* yh = (__bf16*)carve(P * 2); __bf16* yl = (__bf16*)carve(P * 2); __bf16* ys2 = (__bf16*)carve(P * 2);
  float* out_loc = (float*)d_out;
  float* out_sc  = out_loc + P;

  dim3 blk(256);
  conv_all<<<5120, blk, 0, stream>>>(Qloc, Qsc, Kloc, Ksc, Vloc, Vsc,
                                     cQh, cQl, cQ2, cKh, cKl, cK2, cVh, cVl, cV2,
                                     Wq, Wk, Wv, Wo,
                                     wqh, wql, wkh, wkl, wvh, wvl, woh, wol);
  PArg3 pq;
  pq.a[0] = PArg{cQh, cQl, cQ2, wqh, wql, bq, qmh, qml, qm2, qmv, 0};
  pq.a[1] = PArg{cKh, cKl, cK2, wkh, wkl, bk, kmh, kml, km2, kmv, 0};
  pq.a[2] = PArg{cVh, cVl, cV2, wvh, wvl, bv, vTh, vTl, vTv, nullptr, 1};
  dgemm_qkv<<<dim3(8, 32, 3), blk, 0, stream>>>(pq);
  score_mfma<<<dim3(8, 8, 64), blk, 0, stream>>>(qmh, qml, qm2, qmv, kmh, kml, km2, kmv, lmu, lvr, tau);
  attn_kernel<<<dim3((unsigned)(BHS_ / 4)), blk, 0, stream>>>(lmu, lvr, eps, ath, atl);
  pv_mfma<<<dim3(8, 64), blk, 0, stream>>>(ath, atl, vTh, vTl, vTv, yh, yl, ys2);
  dgemm_o<<<dim3(8, 32), blk, 0, stream>>>(yh, yl, ys2, woh, wol, bo, out_loc, out_sc);
}